// Round 12
// baseline (5584.607 us; speedup 1.0000x reference)
//
#include <hip/hip_runtime.h>
#include <hip/hip_bf16.h>
#include <math.h>

#define T_LEN   1024
#define EMB     300
#define EMBP    320
#define HID     512
#define TAGSET  22
#define START_TAG 20
#define END_TAG   21
#define SENT    0xFFFFFFFFu   // memset(0xFF) = negative qNaN; h=sig*tanh can never be NaN

typedef float f32x4 __attribute__((ext_vector_type(4)));

// fast gate math (proven absmax 0.0 in rounds 9-11): __expf-based sigmoid/tanh
__device__ __forceinline__ float fsig(float x) { return 1.f / (1.f + __expf(-x)); }
__device__ __forceinline__ float ftanh(float x) {
    float t = __expf(fminf(2.f * x, 80.f));
    return (t - 1.f) / (t + 1.f);
}

// ---------------- gather + pad ----------------
__global__ void gather_pad_x(const int* __restrict__ ids, const float* __restrict__ emb,
                             float* __restrict__ xp) {
    int t = blockIdx.x;
    int id = ids[t];
    for (int k = threadIdx.x; k < EMBP; k += blockDim.x)
        xp[t * EMBP + k] = (k < EMB) ? emb[(size_t)id * EMB + k] : 0.f;
}

__global__ void pad_w(const float* __restrict__ w, float* __restrict__ wp) {
    int r = blockIdx.x;
    for (int k = threadIdx.x; k < EMBP; k += blockDim.x)
        wp[r * EMBP + k] = (k < EMB) ? w[(size_t)r * EMB + k] : 0.f;
}

// ---------------- fp32 GEMM: C[M][N] = A[M][K] @ B[N][K]^T + bias[N] ----------------
#define BM 64
#define BN 64
#define BK 32
__launch_bounds__(256)
__global__ void gemm_nt(const float* __restrict__ A, const float* __restrict__ B,
                        const float* __restrict__ bias, float* __restrict__ C,
                        int K, int ldc) {
    __shared__ float As[BK][BM + 4];
    __shared__ float Bs[BK][BN + 4];
    const int bm = blockIdx.y * BM, bn = blockIdx.x * BN;
    const int tid = threadIdx.x;
    const int tx = tid & 15, ty = tid >> 4;
    const int lrow = tid >> 2, lk = (tid & 3) * 8;
    float acc[4][4] = {};
    for (int k0 = 0; k0 < K; k0 += BK) {
        float4 a0 = *(const float4*)(A + (size_t)(bm + lrow) * K + k0 + lk);
        float4 a1 = *(const float4*)(A + (size_t)(bm + lrow) * K + k0 + lk + 4);
        float4 b0 = *(const float4*)(B + (size_t)(bn + lrow) * K + k0 + lk);
        float4 b1 = *(const float4*)(B + (size_t)(bn + lrow) * K + k0 + lk + 4);
        __syncthreads();
        As[lk + 0][lrow] = a0.x; As[lk + 1][lrow] = a0.y;
        As[lk + 2][lrow] = a0.z; As[lk + 3][lrow] = a0.w;
        As[lk + 4][lrow] = a1.x; As[lk + 5][lrow] = a1.y;
        As[lk + 6][lrow] = a1.z; As[lk + 7][lrow] = a1.w;
        Bs[lk + 0][lrow] = b0.x; Bs[lk + 1][lrow] = b0.y;
        Bs[lk + 2][lrow] = b0.z; Bs[lk + 3][lrow] = b0.w;
        Bs[lk + 4][lrow] = b1.x; Bs[lk + 5][lrow] = b1.y;
        Bs[lk + 6][lrow] = b1.z; Bs[lk + 7][lrow] = b1.w;
        __syncthreads();
        #pragma unroll
        for (int kk = 0; kk < BK; ++kk) {
            float4 av = *(const float4*)&As[kk][ty * 4];
            float4 bv = *(const float4*)&Bs[kk][tx * 4];
            acc[0][0] += av.x * bv.x; acc[0][1] += av.x * bv.y; acc[0][2] += av.x * bv.z; acc[0][3] += av.x * bv.w;
            acc[1][0] += av.y * bv.x; acc[1][1] += av.y * bv.y; acc[1][2] += av.y * bv.z; acc[1][3] += av.y * bv.w;
            acc[2][0] += av.z * bv.x; acc[2][1] += av.z * bv.y; acc[2][2] += av.z * bv.z; acc[2][3] += av.z * bv.w;
            acc[3][0] += av.w * bv.x; acc[3][1] += av.w * bv.y; acc[3][2] += av.w * bv.z; acc[3][3] += av.w * bv.w;
        }
    }
    const int n = bn + tx * 4;
    #pragma unroll
    for (int i = 0; i < 4; ++i) {
        float4 o;
        o.x = acc[i][0] + bias[n + 0];
        o.y = acc[i][1] + bias[n + 1];
        o.z = acc[i][2] + bias[n + 2];
        o.w = acc[i][3] + bias[n + 3];
        *(float4*)(C + (size_t)(bm + ty * 4 + i) * ldc + n) = o;
    }
}

// ---- macro-expanded weight fragments (r7-exact handling: compiler L2-stream) ----
#define W_LIST(F) F(0) F(1) F(2) F(3) F(4) F(5) F(6) F(7) \
                  F(8) F(9) F(10) F(11) F(12) F(13) F(14) F(15) \
                  F(16) F(17) F(18) F(19) F(20) F(21) F(22) F(23) \
                  F(24) F(25) F(26) F(27) F(28) F(29) F(30) F(31)
#define DECLW(n) f32x4 W##n = wr4[n];
#define PINW(n)  asm volatile("" : "+v"(W##n));
#define DOTW(n, A) { f32x4 hv = hp4[n]; \
    A += W##n[0]*hv[0] + W##n[1]*hv[1] + W##n[2]*hv[2] + W##n[3]*hv[3]; }

// ---------------- distributed LSTM recurrence (intra-wave gates, 1 barrier/step) ----------------
// 64 blocks x 256 threads: blocks [0,32) forward chain, [32,64) backward.
// WG w owns h [w*16,w*16+16); wave v owns 4 h END-TO-END (all 4 gates in-wave).
// Lane = a*16 + g*4 + q: gate row (g*512 + w*16 + v*4 + a), k-quarter q.
// Per step: wave0 polls h(t-1) from L3 (relaxed agent atomics, sentinel
// protocol) -> double-buffered LDS; ONE __syncthreads; all waves dot
// (broadcast LDS reads); xor-reduce over q; 3 in-wave shfl gate gather
// (replaces the old gd-LDS exchange + second barrier); lanes a*16 compute
// gates (fast __expf) and fire the relaxed-agent h store.
// hs[2] race-freedom: a wave finishes its step-t ds_reads (program order)
// before reaching B1(t+1); wave0 stages t+1 into the OTHER buffer.
__launch_bounds__(256, 1)
__global__ void lstm_rec(const float* __restrict__ whh_f, const float* __restrict__ whh_b,
                         const float* __restrict__ pre_f, const float* __restrict__ pre_b,
                         const float* __restrict__ h0, const float* __restrict__ c0,
                         float* __restrict__ hout) {
    const int dir = blockIdx.x >> 5;
    const int w   = blockIdx.x & 31;
    const float* whh = dir ? whh_b : whh_f;
    const float* pre = dir ? pre_b : pre_f;
    const int tid = threadIdx.x;
    const int wv  = tid >> 6;            // wave 0..3
    const int ln  = tid & 63;            // lane 0..63
    const int a   = ln >> 4;             // h within wave 0..3
    const int g   = (ln >> 2) & 3;       // gate 0..3 (i,f,g,o)
    const int q   = ln & 3;              // k-quarter 0..3
    const int hidx = w * 16 + wv * 4 + a;      // h index 0..511
    const int grow = g * 512 + hidx;           // gate row 0..2047

    const f32x4* wr4 = (const f32x4*)(whh + (size_t)grow * 512 + q * 128);
    W_LIST(DECLW)
    W_LIST(PINW)

    __shared__ float hs[2][528];         // double-buffered; quarter stride 132
    const bool isprod = ((ln & 15) == 0);      // lanes a*16 (g=0,q=0)
    float c_reg = 0.f;
    if (isprod) c_reg = c0[dir * 512 + hidx];
    const int col = dir * 512;

    for (int t = 0; t < 1024; ++t) {
        const int pos = dir ? (1023 - t) : t;
        // prefetch input-projection gate biases (off critical path)
        float pf_i = 0.f, pf_f = 0.f, pf_g = 0.f, pf_o = 0.f;
        if (isprod) {
            const float* pr = pre + (size_t)pos * 2048 + hidx;
            pf_i = pr[0]; pf_f = pr[512]; pf_g = pr[1024]; pf_o = pr[1536];
        }
        const int buf = t & 1;
        // wave0: acquire previous h row into LDS
        if (tid < 64) {
            unsigned v[8];
            if (t == 0) {
                const float* src = h0 + dir * 512 + tid * 8;
                #pragma unroll
                for (int i = 0; i < 8; ++i) v[i] = __float_as_uint(src[i]);
            } else {
                const unsigned* src =
                    (const unsigned*)(hout + (size_t)(dir ? pos + 1 : pos - 1) * 1024 + col) + tid * 8;
                bool done = false;
                unsigned long long pend;
                do {
                    if (!done) {
                        #pragma unroll
                        for (int i = 0; i < 8; ++i)
                            v[i] = __hip_atomic_load(&src[i], __ATOMIC_RELAXED,
                                                     __HIP_MEMORY_SCOPE_AGENT);
                        done = true;
                        #pragma unroll
                        for (int i = 0; i < 8; ++i) done = done && (v[i] != SENT);
                    }
                    pend = __ballot(!done);
                } while (pend);
            }
            const int qq = tid >> 4, base = (tid & 15) * 8;
            #pragma unroll
            for (int i = 0; i < 8; ++i) hs[buf][qq * 132 + base + i] = __uint_as_float(v[i]);
        }
        __syncthreads();                 // B1: hs[buf] staged (only barrier per step)
        const f32x4* hp4 = (const f32x4*)&hs[buf][q * 132];
        float ac0 = 0.f, ac1 = 0.f, ac2 = 0.f, ac3 = 0.f;
        DOTW(0, ac0)  DOTW(1, ac1)  DOTW(2, ac2)  DOTW(3, ac3)
        DOTW(4, ac0)  DOTW(5, ac1)  DOTW(6, ac2)  DOTW(7, ac3)
        DOTW(8, ac0)  DOTW(9, ac1)  DOTW(10, ac2) DOTW(11, ac3)
        DOTW(12, ac0) DOTW(13, ac1) DOTW(14, ac2) DOTW(15, ac3)
        DOTW(16, ac0) DOTW(17, ac1) DOTW(18, ac2) DOTW(19, ac3)
        DOTW(20, ac0) DOTW(21, ac1) DOTW(22, ac2) DOTW(23, ac3)
        DOTW(24, ac0) DOTW(25, ac1) DOTW(26, ac2) DOTW(27, ac3)
        DOTW(28, ac0) DOTW(29, ac1) DOTW(30, ac2) DOTW(31, ac3)
        float acc = (ac0 + ac1) + (ac2 + ac3);
        acc += __shfl_xor(acc, 1);       // reduce over q
        acc += __shfl_xor(acc, 2);
        const int gb = ln & 48;          // a*16: base lane of this h's gate group
        float gf = __shfl(acc, gb + 4);
        float gg = __shfl(acc, gb + 8);
        float go = __shfl(acc, gb + 12);
        if (isprod) {
            float gi = acc + pf_i;
            gf += pf_f; gg += pf_g; go += pf_o;
            float c = fsig(gf) * c_reg + fsig(gi) * ftanh(gg);
            float h = fsig(go) * ftanh(c);
            c_reg = c;
            __hip_atomic_store(&hout[(size_t)pos * 1024 + col + hidx], h,
                               __ATOMIC_RELAXED, __HIP_MEMORY_SCOPE_AGENT);
        }
    }
}

// ---------------- feats = dec_cat @ lin_w^T + lin_b ----------------
__global__ void feats_kernel(const float* __restrict__ dc, const float* __restrict__ lw,
                             const float* __restrict__ lb, float* __restrict__ ft) {
    const int t = blockIdx.x;
    const int tid = threadIdx.x;
    const int j = tid >> 3, s = tid & 7;
    if (j >= TAGSET) return;
    const float4* a = (const float4*)(dc + (size_t)t * 1024);
    const float4* wv = (const float4*)(lw + (size_t)j * 1024);
    float acc = 0.f;
    #pragma unroll
    for (int i = 0; i < 32; ++i) {
        float4 av = a[s + 8 * i];
        float4 ww = wv[s + 8 * i];
        acc += av.x * ww.x + av.y * ww.y + av.z * ww.z + av.w * ww.w;
    }
    acc += __shfl_xor(acc, 1);
    acc += __shfl_xor(acc, 2);
    acc += __shfl_xor(acc, 4);
    if (s == 0) ft[t * TAGSET + j] = acc + lb[j];
}

// ---- CRF helper macros: 22 register-resident transition-column values ----
#define TR_LIST(F) F(0) F(1) F(2) F(3) F(4) F(5) F(6) F(7) F(8) F(9) F(10) \
                   F(11) F(12) F(13) F(14) F(15) F(16) F(17) F(18) F(19) F(20) F(21)
#define DECLTR(i) float trc##i = trans[i * TAGSET + jj];
#define VDEF(i)   float v##i = sm[i] + trc##i;
#define ESUM(i)   e##i = __expf(v##i - m);
#define MAXTREE(m) { \
    float m0 = fmaxf(v0, v1),  m1 = fmaxf(v2, v3),  m2_ = fmaxf(v4, v5),  m3 = fmaxf(v6, v7); \
    float m4 = fmaxf(v8, v9),  m5 = fmaxf(v10, v11), m6 = fmaxf(v12, v13), m7 = fmaxf(v14, v15); \
    float m8 = fmaxf(v16, v17), m9 = fmaxf(v18, v19), m10 = fmaxf(v20, v21); \
    float n0 = fmaxf(m0, m1), n1 = fmaxf(m2_, m3), n2 = fmaxf(m4, m5), n3 = fmaxf(m6, m7); \
    float n4 = fmaxf(m8, m9); \
    float p0 = fmaxf(n0, n1), p1 = fmaxf(n2, n3), p2 = fmaxf(n4, m10); \
    m = fmaxf(fmaxf(p0, p1), p2); }
#define VITSTEP(i) { float v_ = sm[i] + trc##i; \
    if (v_ > best) { best = v_; arg = i; } }

// ---------------- CRF: block 0 = forward LSE + gold + loss; block 1 = Viterbi ----------------
__launch_bounds__(128)
__global__ void crf_kernel(const float* __restrict__ ft, const float* __restrict__ trans,
                           const int* __restrict__ tags, float* __restrict__ out) {
    __shared__ float tr[TAGSET * TAGSET];
    __shared__ unsigned char bps[1024][TAGSET];
    __shared__ float res[2];
    const int tid = threadIdx.x;
    for (int i = tid; i < TAGSET * TAGSET; i += blockDim.x) tr[i] = trans[i];
    __syncthreads();

    if (blockIdx.x == 0) {
        if (tid < 64) {
            __shared__ float sm[32];
            const int j = tid;
            const int jj = (j < TAGSET) ? j : 0;
            TR_LIST(DECLTR)
            float trEnd = trans[jj * TAGSET + END_TAG];
            float alpha = (j == START_TAG) ? 0.f : -10000.f;
            float ftc = ft[jj];
            for (int t = 0; t < 1024; ++t) {
                float ftn = (t < 1023) ? ft[(t + 1) * TAGSET + jj] : 0.f;
                if (j < TAGSET) sm[j] = alpha;
                TR_LIST(VDEF)
                float m; MAXTREE(m)
                float e0,e1,e2,e3,e4,e5,e6,e7,e8,e9,e10,e11,e12,e13,e14,e15,e16,e17,e18,e19,e20,e21;
                TR_LIST(ESUM)
                float s0 = ((e0+e1)+(e2+e3)) + ((e4+e5)+(e6+e7));
                float s1 = ((e8+e9)+(e10+e11)) + ((e12+e13)+(e14+e15));
                float s2 = ((e16+e17)+(e18+e19)) + (e20+e21);
                alpha = ftc + m + __logf((s0 + s1) + s2);
                ftc = ftn;
            }
            float v = (j < TAGSET) ? (alpha + trEnd) : -3.0e38f;
            float m2 = v;
            for (int d = 1; d < 32; d <<= 1) m2 = fmaxf(m2, __shfl_xor(m2, d));
            float e = (j < TAGSET) ? __expf(v - m2) : 0.f;
            for (int d = 1; d < 32; d <<= 1) e += __shfl_xor(e, d);
            if (tid == 0) res[0] = m2 + __logf(e);
        } else {
            const int l = tid - 64;
            float gsum = 0.f;
            for (int t = l; t < 1024; t += 64) {
                int cur = tags[t];
                int prev = (t == 0) ? START_TAG : tags[t - 1];
                gsum += tr[prev * TAGSET + cur] + ft[t * TAGSET + cur];
            }
            for (int d = 1; d < 64; d <<= 1) gsum += __shfl_xor(gsum, d);
            if (l == 0) res[1] = gsum + tr[tags[1023] * TAGSET + END_TAG];
        }
        __syncthreads();
        if (tid == 0) out[1024] = res[0] - res[1];
    } else {
        if (tid < 64) {
            __shared__ float sm[32];
            const int j = tid;
            const int jj = (j < TAGSET) ? j : 0;
            TR_LIST(DECLTR)
            float trEnd = trans[jj * TAGSET + END_TAG];
            float a = (j == START_TAG) ? 0.f : -10000.f;
            float ftc = ft[jj];
            for (int t = 0; t < 1024; ++t) {
                float ftn = (t < 1023) ? ft[(t + 1) * TAGSET + jj] : 0.f;
                if (j < TAGSET) sm[j] = a;
                float best = -3.4e38f; int arg = 0;
                VITSTEP(0)  VITSTEP(1)  VITSTEP(2)  VITSTEP(3)  VITSTEP(4)  VITSTEP(5)
                VITSTEP(6)  VITSTEP(7)  VITSTEP(8)  VITSTEP(9)  VITSTEP(10) VITSTEP(11)
                VITSTEP(12) VITSTEP(13) VITSTEP(14) VITSTEP(15) VITSTEP(16) VITSTEP(17)
                VITSTEP(18) VITSTEP(19) VITSTEP(20) VITSTEP(21)
                if (j < TAGSET) bps[t][j] = (unsigned char)arg;
                a = best + ftc;
                ftc = ftn;
            }
            float v = (j < TAGSET) ? (a + trEnd) : -3.4e38f;
            float bb = -3.4e38f; int bl = 0;
            for (int i = 0; i < TAGSET; ++i) {
                float vi = __shfl(v, i);
                if (vi > bb) { bb = vi; bl = i; }
            }
            __threadfence_block();
            if (tid == 0) {
                int cur = bl;
                out[1023] = (float)cur;
                for (int t = 1023; t >= 1; --t) {
                    cur = bps[t][cur];
                    out[t - 1] = (float)cur;
                }
            }
        }
    }
}

// ---------------- launcher ----------------
extern "C" void kernel_launch(void* const* d_in, const int* in_sizes, int n_in,
                              void* d_out, int out_size, void* d_ws, size_t ws_size,
                              hipStream_t stream) {
    const int*   ids   = (const int*)d_in[0];
    const int*   tags  = (const int*)d_in[1];
    const float* emb   = (const float*)d_in[2];
    const float* e_wif = (const float*)d_in[3];
    const float* e_whf = (const float*)d_in[4];
    const float* e_bf  = (const float*)d_in[5];
    const float* e_wib = (const float*)d_in[6];
    const float* e_whb = (const float*)d_in[7];
    const float* e_bb  = (const float*)d_in[8];
    const float* d_wif = (const float*)d_in[9];
    const float* d_whf = (const float*)d_in[10];
    const float* d_bf  = (const float*)d_in[11];
    const float* d_wib = (const float*)d_in[12];
    const float* d_whb = (const float*)d_in[13];
    const float* d_bb  = (const float*)d_in[14];
    const float* lw    = (const float*)d_in[15];
    const float* lb    = (const float*)d_in[16];
    const float* trp   = (const float*)d_in[17];
    const float* h0    = (const float*)d_in[18];
    const float* c0    = (const float*)d_in[19];
    float* out = (float*)d_out;

    // workspace layout (floats)
    float* ws    = (float*)d_ws;
    float* xp    = ws;                       // 1024*320
    float* wpf   = xp    + 1024 * 320;       // 2048*320
    float* wpb   = wpf   + 2048 * 320;       // 2048*320
    float* pre_f = wpb   + 2048 * 320;       // 1024*2048
    float* pre_b = pre_f + 1024 * 2048;      // 1024*2048
    float* ecat  = pre_b + 1024 * 2048;      // 1024*1024
    float* dcat  = ecat  + 1024 * 1024;      // 1024*1024
    float* ft    = dcat  + 1024 * 1024;      // 1024*32 (uses 22)

    // sentinel-fill the h buffers (0xFF bytes = qNaN; LSTM h can never be NaN)
    hipMemsetAsync(ecat, 0xFF, 1024 * 1024 * sizeof(float), stream);
    hipMemsetAsync(dcat, 0xFF, 1024 * 1024 * sizeof(float), stream);

    gather_pad_x<<<1024, 256, 0, stream>>>(ids, emb, xp);
    pad_w<<<2048, 256, 0, stream>>>(e_wif, wpf);
    pad_w<<<2048, 256, 0, stream>>>(e_wib, wpb);

    dim3 gg(2048 / BN, 1024 / BM);
    gemm_nt<<<gg, 256, 0, stream>>>(xp, wpf, e_bf, pre_f, EMBP, 2048);
    gemm_nt<<<gg, 256, 0, stream>>>(xp, wpb, e_bb, pre_b, EMBP, 2048);

    lstm_rec<<<64, 256, 0, stream>>>(e_whf, e_whb, pre_f, pre_b, h0, c0, ecat);

    gemm_nt<<<gg, 256, 0, stream>>>(ecat, d_wif, d_bf, pre_f, 1024, 2048);
    gemm_nt<<<gg, 256, 0, stream>>>(ecat, d_wib, d_bb, pre_b, 1024, 2048);

    lstm_rec<<<64, 256, 0, stream>>>(d_whf, d_whb, pre_f, pre_b, h0, c0, dcat);

    feats_kernel<<<1024, 256, 0, stream>>>(dcat, lw, lb, ft);
    crf_kernel<<<2, 128, 0, stream>>>(ft, trp, tags, out);
}

// Round 13
// 4532.858 us; speedup vs baseline: 1.2320x; 1.2320x over previous
//
#include <hip/hip_runtime.h>
#include <hip/hip_bf16.h>
#include <math.h>

#define T_LEN   1024
#define EMB     300
#define EMBP    320
#define HID     512
#define TAGSET  22
#define START_TAG 20
#define END_TAG   21
#define SENT    0xFFFFFFFFu   // memset(0xFF) = negative qNaN; h=sig*tanh can never be NaN

typedef float f32x4 __attribute__((ext_vector_type(4)));

__device__ __forceinline__ float sigf(float x) { return 1.f / (1.f + expf(-x)); }

// ---------------- gather + pad ----------------
__global__ void gather_pad_x(const int* __restrict__ ids, const float* __restrict__ emb,
                             float* __restrict__ xp) {
    int t = blockIdx.x;
    int id = ids[t];
    for (int k = threadIdx.x; k < EMBP; k += blockDim.x)
        xp[t * EMBP + k] = (k < EMB) ? emb[(size_t)id * EMB + k] : 0.f;
}

__global__ void pad_w(const float* __restrict__ w, float* __restrict__ wp) {
    int r = blockIdx.x;
    for (int k = threadIdx.x; k < EMBP; k += blockDim.x)
        wp[r * EMBP + k] = (k < EMB) ? w[(size_t)r * EMB + k] : 0.f;
}

// ---------------- fp32 GEMM: C[M][N] = A[M][K] @ B[N][K]^T + bias[N] ----------------
#define BM 64
#define BN 64
#define BK 32
__launch_bounds__(256)
__global__ void gemm_nt(const float* __restrict__ A, const float* __restrict__ B,
                        const float* __restrict__ bias, float* __restrict__ C,
                        int K, int ldc) {
    __shared__ float As[BK][BM + 4];
    __shared__ float Bs[BK][BN + 4];
    const int bm = blockIdx.y * BM, bn = blockIdx.x * BN;
    const int tid = threadIdx.x;
    const int tx = tid & 15, ty = tid >> 4;
    const int lrow = tid >> 2, lk = (tid & 3) * 8;
    float acc[4][4] = {};
    for (int k0 = 0; k0 < K; k0 += BK) {
        float4 a0 = *(const float4*)(A + (size_t)(bm + lrow) * K + k0 + lk);
        float4 a1 = *(const float4*)(A + (size_t)(bm + lrow) * K + k0 + lk + 4);
        float4 b0 = *(const float4*)(B + (size_t)(bn + lrow) * K + k0 + lk);
        float4 b1 = *(const float4*)(B + (size_t)(bn + lrow) * K + k0 + lk + 4);
        __syncthreads();
        As[lk + 0][lrow] = a0.x; As[lk + 1][lrow] = a0.y;
        As[lk + 2][lrow] = a0.z; As[lk + 3][lrow] = a0.w;
        As[lk + 4][lrow] = a1.x; As[lk + 5][lrow] = a1.y;
        As[lk + 6][lrow] = a1.z; As[lk + 7][lrow] = a1.w;
        Bs[lk + 0][lrow] = b0.x; Bs[lk + 1][lrow] = b0.y;
        Bs[lk + 2][lrow] = b0.z; Bs[lk + 3][lrow] = b0.w;
        Bs[lk + 4][lrow] = b1.x; Bs[lk + 5][lrow] = b1.y;
        Bs[lk + 6][lrow] = b1.z; Bs[lk + 7][lrow] = b1.w;
        __syncthreads();
        #pragma unroll
        for (int kk = 0; kk < BK; ++kk) {
            float4 av = *(const float4*)&As[kk][ty * 4];
            float4 bv = *(const float4*)&Bs[kk][tx * 4];
            acc[0][0] += av.x * bv.x; acc[0][1] += av.x * bv.y; acc[0][2] += av.x * bv.z; acc[0][3] += av.x * bv.w;
            acc[1][0] += av.y * bv.x; acc[1][1] += av.y * bv.y; acc[1][2] += av.y * bv.z; acc[1][3] += av.y * bv.w;
            acc[2][0] += av.z * bv.x; acc[2][1] += av.z * bv.y; acc[2][2] += av.z * bv.z; acc[2][3] += av.z * bv.w;
            acc[3][0] += av.w * bv.x; acc[3][1] += av.w * bv.y; acc[3][2] += av.w * bv.z; acc[3][3] += av.w * bv.w;
        }
    }
    const int n = bn + tx * 4;
    #pragma unroll
    for (int i = 0; i < 4; ++i) {
        float4 o;
        o.x = acc[i][0] + bias[n + 0];
        o.y = acc[i][1] + bias[n + 1];
        o.z = acc[i][2] + bias[n + 2];
        o.w = acc[i][3] + bias[n + 3];
        *(float4*)(C + (size_t)(bm + ty * 4 + i) * ldc + n) = o;
    }
}

// ---- macro-expanded weight fragments (named vars: direct asm operands) ----
#define W_LIST(F) F(0) F(1) F(2) F(3) F(4) F(5) F(6) F(7) \
                  F(8) F(9) F(10) F(11) F(12) F(13) F(14) F(15) \
                  F(16) F(17) F(18) F(19) F(20) F(21) F(22) F(23) \
                  F(24) F(25) F(26) F(27) F(28) F(29) F(30) F(31)
#define DECLW(n) f32x4 W##n = wr4[n];
#define PINW(n)  asm volatile("" : "+v"(W##n));
#define DOTW(n, A) { f32x4 hv = hp4[n]; \
    A += W##n[0]*hv[0] + W##n[1]*hv[1] + W##n[2]*hv[2] + W##n[3]*hv[3]; }

// ---------------- distributed LSTM recurrence (poll-on-data, L3 relaxed atomics) ----------------
// 64 blocks x 256 threads: blocks [0,32) forward chain, [32,64) backward.
// WG w owns h-indices [w*16,w*16+16) -> 64 gate rows of W_hh. Handshake = ONE
// L3 transaction per step: producers (wave0 lanes 0-15, ONE coalesced 64B
// burst) fire relaxed agent-scope h-stores; NO flags, NO vmcnt. hout is
// pre-filled with 0xFFFFFFFF (qNaN) sentinels; consumers poll the data itself
// with relaxed agent-scope loads (wave0: 64 lanes x 8 dwords = full 512-float
// row), bounce through padded LDS, all 4 waves dot from LDS.
__launch_bounds__(256, 1)
__global__ void lstm_rec(const float* __restrict__ whh_f, const float* __restrict__ whh_b,
                         const float* __restrict__ pre_f, const float* __restrict__ pre_b,
                         const float* __restrict__ h0, const float* __restrict__ c0,
                         float* __restrict__ hout) {
    const int dir = blockIdx.x >> 5;
    const int w   = blockIdx.x & 31;
    const float* whh = dir ? whh_b : whh_f;
    const float* pre = dir ? pre_b : pre_f;
    const int tid = threadIdx.x;
    const int lr = tid >> 2, q = tid & 3;    // local gate-row 0..63, k-quarter 0..3
    const int g = lr >> 4, j = lr & 15;      // gate, local h index
    const int grow = g * 512 + w * 16 + j;   // gate row in [0,2048)

    const f32x4* wr4 = (const f32x4*)(whh + (size_t)grow * 512 + q * 128);
    W_LIST(DECLW)
    W_LIST(PINW)

    __shared__ float hs[4 * 132];            // q-major, pad 132 -> conflict-free reads
    __shared__ float gd[4][16];
    float c_reg = 0.f;
    if (tid < 16) c_reg = c0[dir * 512 + w * 16 + tid];
    const int col = dir * 512;

    for (int t = 0; t < 1024; ++t) {
        const int pos = dir ? (1023 - t) : t;
        // prefetch input-projection rows for this step (hides under the poll)
        float pf_i = 0.f, pf_f = 0.f, pf_g = 0.f, pf_o = 0.f;
        if (tid < 16) {
            const float* pr = pre + (size_t)pos * 2048 + w * 16 + tid;
            pf_i = pr[0]; pf_f = pr[512]; pf_g = pr[1024]; pf_o = pr[1536];
        }
        // wave0: acquire previous h row into LDS
        if (tid < 64) {
            unsigned v[8];
            if (t == 0) {
                const float* src = h0 + dir * 512 + tid * 8;
                #pragma unroll
                for (int i = 0; i < 8; ++i) v[i] = __float_as_uint(src[i]);
            } else {
                const unsigned* src =
                    (const unsigned*)(hout + (size_t)(dir ? pos + 1 : pos - 1) * 1024 + col) + tid * 8;
                bool done = false;
                unsigned long long pend;
                do {
                    if (!done) {
                        #pragma unroll
                        for (int i = 0; i < 8; ++i)
                            v[i] = __hip_atomic_load(&src[i], __ATOMIC_RELAXED,
                                                     __HIP_MEMORY_SCOPE_AGENT);
                        done = true;
                        #pragma unroll
                        for (int i = 0; i < 8; ++i) done = done && (v[i] != SENT);
                    }
                    pend = __ballot(!done);
                } while (pend);
            }
            const int qq = tid >> 4, base = (tid & 15) * 8;
            #pragma unroll
            for (int i = 0; i < 8; ++i) hs[qq * 132 + base + i] = __uint_as_float(v[i]);
        }
        __syncthreads();                     // B1: hs ready
        const f32x4* hp4 = (const f32x4*)&hs[q * 132];
        float ac0 = 0.f, ac1 = 0.f, ac2 = 0.f, ac3 = 0.f;
        DOTW(0, ac0)  DOTW(1, ac1)  DOTW(2, ac2)  DOTW(3, ac3)
        DOTW(4, ac0)  DOTW(5, ac1)  DOTW(6, ac2)  DOTW(7, ac3)
        DOTW(8, ac0)  DOTW(9, ac1)  DOTW(10, ac2) DOTW(11, ac3)
        DOTW(12, ac0) DOTW(13, ac1) DOTW(14, ac2) DOTW(15, ac3)
        DOTW(16, ac0) DOTW(17, ac1) DOTW(18, ac2) DOTW(19, ac3)
        DOTW(20, ac0) DOTW(21, ac1) DOTW(22, ac2) DOTW(23, ac3)
        DOTW(24, ac0) DOTW(25, ac1) DOTW(26, ac2) DOTW(27, ac3)
        DOTW(28, ac0) DOTW(29, ac1) DOTW(30, ac2) DOTW(31, ac3)
        float acc = (ac0 + ac1) + (ac2 + ac3);
        acc += __shfl_xor(acc, 1);
        acc += __shfl_xor(acc, 2);
        if (q == 0) gd[g][j] = acc;
        __syncthreads();                     // B2: gd ready (also fences hs reuse)
        if (tid < 16) {
            float gi = gd[0][tid] + pf_i;
            float gf = gd[1][tid] + pf_f;
            float gg = gd[2][tid] + pf_g;
            float go = gd[3][tid] + pf_o;
            float c = sigf(gf) * c_reg + sigf(gi) * tanhf(gg);
            float h = sigf(go) * tanhf(c);
            c_reg = c;
            // fire-and-forget: the data write IS the signal (sentinel -> value)
            __hip_atomic_store(&hout[(size_t)pos * 1024 + col + w * 16 + tid], h,
                               __ATOMIC_RELAXED, __HIP_MEMORY_SCOPE_AGENT);
        }
    }
}

// ---------------- feats = dec_cat @ lin_w^T + lin_b ----------------
__global__ void feats_kernel(const float* __restrict__ dc, const float* __restrict__ lw,
                             const float* __restrict__ lb, float* __restrict__ ft) {
    const int t = blockIdx.x;
    const int tid = threadIdx.x;
    const int j = tid >> 3, s = tid & 7;
    if (j >= TAGSET) return;
    const float4* a = (const float4*)(dc + (size_t)t * 1024);
    const float4* wv = (const float4*)(lw + (size_t)j * 1024);
    float acc = 0.f;
    #pragma unroll
    for (int i = 0; i < 32; ++i) {
        float4 av = a[s + 8 * i];
        float4 ww = wv[s + 8 * i];
        acc += av.x * ww.x + av.y * ww.y + av.z * ww.z + av.w * ww.w;
    }
    acc += __shfl_xor(acc, 1);
    acc += __shfl_xor(acc, 2);
    acc += __shfl_xor(acc, 4);
    if (s == 0) ft[t * TAGSET + j] = acc + lb[j];
}

// ---- CRF helper macros: 22 register-resident transition-column values ----
#define TR_LIST(F) F(0) F(1) F(2) F(3) F(4) F(5) F(6) F(7) F(8) F(9) F(10) \
                   F(11) F(12) F(13) F(14) F(15) F(16) F(17) F(18) F(19) F(20) F(21)
#define DECLTR(i) float trc##i = trans[i * TAGSET + jj];
#define VDEF(i)   float v##i = sm[i] + trc##i;
#define ESUM(i)   e##i = __expf(v##i - m);
// pairwise max tree over v0..v21 (depth 5)
#define MAXTREE(m) { \
    float m0 = fmaxf(v0, v1),  m1 = fmaxf(v2, v3),  m2_ = fmaxf(v4, v5),  m3 = fmaxf(v6, v7); \
    float m4 = fmaxf(v8, v9),  m5 = fmaxf(v10, v11), m6 = fmaxf(v12, v13), m7 = fmaxf(v14, v15); \
    float m8 = fmaxf(v16, v17), m9 = fmaxf(v18, v19), m10 = fmaxf(v20, v21); \
    float n0 = fmaxf(m0, m1), n1 = fmaxf(m2_, m3), n2 = fmaxf(m4, m5), n3 = fmaxf(m6, m7); \
    float n4 = fmaxf(m8, m9); \
    float p0 = fmaxf(n0, n1), p1 = fmaxf(n2, n3), p2 = fmaxf(n4, m10); \
    m = fmaxf(fmaxf(p0, p1), p2); }
#define VITSTEP(i) { float v_ = sm[i] + trc##i; \
    if (v_ > best) { best = v_; arg = i; } }

// ---------------- CRF: block 0 = forward LSE + gold + loss; block 1 = Viterbi ----------------
// Serial-path design: per step, alpha is exchanged through ONE LDS write +
// 22 broadcast LDS reads (pipelined) instead of 44 serial __shfl.
__launch_bounds__(128)
__global__ void crf_kernel(const float* __restrict__ ft, const float* __restrict__ trans,
                           const int* __restrict__ tags, float* __restrict__ out) {
    __shared__ float tr[TAGSET * TAGSET];
    __shared__ unsigned char bps[1024][TAGSET];
    __shared__ float res[2];
    const int tid = threadIdx.x;
    for (int i = tid; i < TAGSET * TAGSET; i += blockDim.x) tr[i] = trans[i];
    __syncthreads();

    if (blockIdx.x == 0) {
        if (tid < 64) {
            __shared__ float sm[32];
            const int j = tid;
            const int jj = (j < TAGSET) ? j : 0;   // lanes >=22 compute garbage, never write
            TR_LIST(DECLTR)
            float trEnd = trans[jj * TAGSET + END_TAG];
            float alpha = (j == START_TAG) ? 0.f : -10000.f;
            float ftc = ft[jj];                     // software prefetch of ft[t][j]
            for (int t = 0; t < 1024; ++t) {
                float ftn = (t < 1023) ? ft[(t + 1) * TAGSET + jj] : 0.f;  // off-path load
                if (j < TAGSET) sm[j] = alpha;
                TR_LIST(VDEF)
                float m; MAXTREE(m)
                float e0,e1,e2,e3,e4,e5,e6,e7,e8,e9,e10,e11,e12,e13,e14,e15,e16,e17,e18,e19,e20,e21;
                TR_LIST(ESUM)
                float s0 = ((e0+e1)+(e2+e3)) + ((e4+e5)+(e6+e7));
                float s1 = ((e8+e9)+(e10+e11)) + ((e12+e13)+(e14+e15));
                float s2 = ((e16+e17)+(e18+e19)) + (e20+e21);
                alpha = ftc + m + __logf((s0 + s1) + s2);
                ftc = ftn;
            }
            float v = (j < TAGSET) ? (alpha + trEnd) : -3.0e38f;
            float m2 = v;
            for (int d = 1; d < 32; d <<= 1) m2 = fmaxf(m2, __shfl_xor(m2, d));
            float e = (j < TAGSET) ? __expf(v - m2) : 0.f;
            for (int d = 1; d < 32; d <<= 1) e += __shfl_xor(e, d);
            if (tid == 0) res[0] = m2 + __logf(e);
        } else {
            const int l = tid - 64;
            float gsum = 0.f;
            for (int t = l; t < 1024; t += 64) {
                int cur = tags[t];
                int prev = (t == 0) ? START_TAG : tags[t - 1];
                gsum += tr[prev * TAGSET + cur] + ft[t * TAGSET + cur];
            }
            for (int d = 1; d < 64; d <<= 1) gsum += __shfl_xor(gsum, d);
            if (l == 0) res[1] = gsum + tr[tags[1023] * TAGSET + END_TAG];
        }
        __syncthreads();
        if (tid == 0) out[1024] = res[0] - res[1];
    } else {
        if (tid < 64) {
            __shared__ float sm[32];
            const int j = tid;
            const int jj = (j < TAGSET) ? j : 0;
            TR_LIST(DECLTR)
            float trEnd = trans[jj * TAGSET + END_TAG];
            float a = (j == START_TAG) ? 0.f : -10000.f;
            float ftc = ft[jj];
            for (int t = 0; t < 1024; ++t) {
                float ftn = (t < 1023) ? ft[(t + 1) * TAGSET + jj] : 0.f;
                if (j < TAGSET) sm[j] = a;
                float best = -3.4e38f; int arg = 0;
                VITSTEP(0)  VITSTEP(1)  VITSTEP(2)  VITSTEP(3)  VITSTEP(4)  VITSTEP(5)
                VITSTEP(6)  VITSTEP(7)  VITSTEP(8)  VITSTEP(9)  VITSTEP(10) VITSTEP(11)
                VITSTEP(12) VITSTEP(13) VITSTEP(14) VITSTEP(15) VITSTEP(16) VITSTEP(17)
                VITSTEP(18) VITSTEP(19) VITSTEP(20) VITSTEP(21)
                if (j < TAGSET) bps[t][j] = (unsigned char)arg;
                a = best + ftc;
                ftc = ftn;
            }
            float v = (j < TAGSET) ? (a + trEnd) : -3.4e38f;
            float bb = -3.4e38f; int bl = 0;
            for (int i = 0; i < TAGSET; ++i) {
                float vi = __shfl(v, i);
                if (vi > bb) { bb = vi; bl = i; }
            }
            __threadfence_block();
            if (tid == 0) {
                int cur = bl;
                out[1023] = (float)cur;
                for (int t = 1023; t >= 1; --t) {
                    cur = bps[t][cur];
                    out[t - 1] = (float)cur;
                }
            }
        }
    }
}

// ---------------- launcher ----------------
extern "C" void kernel_launch(void* const* d_in, const int* in_sizes, int n_in,
                              void* d_out, int out_size, void* d_ws, size_t ws_size,
                              hipStream_t stream) {
    const int*   ids   = (const int*)d_in[0];
    const int*   tags  = (const int*)d_in[1];
    const float* emb   = (const float*)d_in[2];
    const float* e_wif = (const float*)d_in[3];
    const float* e_whf = (const float*)d_in[4];
    const float* e_bf  = (const float*)d_in[5];
    const float* e_wib = (const float*)d_in[6];
    const float* e_whb = (const float*)d_in[7];
    const float* e_bb  = (const float*)d_in[8];
    const float* d_wif = (const float*)d_in[9];
    const float* d_whf = (const float*)d_in[10];
    const float* d_bf  = (const float*)d_in[11];
    const float* d_wib = (const float*)d_in[12];
    const float* d_whb = (const float*)d_in[13];
    const float* d_bb  = (const float*)d_in[14];
    const float* lw    = (const float*)d_in[15];
    const float* lb    = (const float*)d_in[16];
    const float* trp   = (const float*)d_in[17];
    const float* h0    = (const float*)d_in[18];
    const float* c0    = (const float*)d_in[19];
    float* out = (float*)d_out;

    // workspace layout (floats)
    float* ws    = (float*)d_ws;
    float* xp    = ws;                       // 1024*320
    float* wpf   = xp    + 1024 * 320;       // 2048*320
    float* wpb   = wpf   + 2048 * 320;       // 2048*320
    float* pre_f = wpb   + 2048 * 320;       // 1024*2048
    float* pre_b = pre_f + 1024 * 2048;      // 1024*2048
    float* ecat  = pre_b + 1024 * 2048;      // 1024*1024
    float* dcat  = ecat  + 1024 * 1024;      // 1024*1024
    float* ft    = dcat  + 1024 * 1024;      // 1024*32 (uses 22)

    // sentinel-fill the h buffers (0xFF bytes = qNaN; LSTM h can never be NaN)
    hipMemsetAsync(ecat, 0xFF, 1024 * 1024 * sizeof(float), stream);
    hipMemsetAsync(dcat, 0xFF, 1024 * 1024 * sizeof(float), stream);

    gather_pad_x<<<1024, 256, 0, stream>>>(ids, emb, xp);
    pad_w<<<2048, 256, 0, stream>>>(e_wif, wpf);
    pad_w<<<2048, 256, 0, stream>>>(e_wib, wpb);

    dim3 gg(2048 / BN, 1024 / BM);
    gemm_nt<<<gg, 256, 0, stream>>>(xp, wpf, e_bf, pre_f, EMBP, 2048);
    gemm_nt<<<gg, 256, 0, stream>>>(xp, wpb, e_bb, pre_b, EMBP, 2048);

    lstm_rec<<<64, 256, 0, stream>>>(e_whf, e_whb, pre_f, pre_b, h0, c0, ecat);

    gemm_nt<<<gg, 256, 0, stream>>>(ecat, d_wif, d_bf, pre_f, 1024, 2048);
    gemm_nt<<<gg, 256, 0, stream>>>(ecat, d_wib, d_bb, pre_b, 1024, 2048);

    lstm_rec<<<64, 256, 0, stream>>>(d_whf, d_whb, pre_f, pre_b, h0, c0, dcat);

    feats_kernel<<<1024, 256, 0, stream>>>(dcat, lw, lb, ft);
    crf_kernel<<<2, 128, 0, stream>>>(ft, trp, tags, out);
}